// Round 2
// baseline (85.763 us; speedup 1.0000x reference)
//
#include <hip/hip_runtime.h>
#include <math.h>

#define K 17
#define WAVE 64
#define G 10
#define CELLS (G*G*G)
#define BCAP 16       // bucket slots per cell
#define OVCAP 128     // global overflow list capacity (E[ov]~5)
#define CAP 128       // per-wave LDS survivor capacity
#define KEY_MAX 0xFFFFFFFFFFFFFFFFULL

__device__ __forceinline__ bool lex_less(float ad, int ai, float bd, int bi) {
    return (ad < bd) || (ad == bd && ai < bi);
}

// ---------- prep v3: scan-free padded buckets, fully parallel (r17-proven) ------

__global__ __launch_bounds__(256) void prep_bucket(
    const float* __restrict__ pos, const float* __restrict__ box,
    int* __restrict__ cnt, int* __restrict__ ovCnt,
    float4* __restrict__ ov, float4* __restrict__ bucket, int N)
{
    const int t = blockIdx.x * 256 + threadIdx.x;
    if (t >= N) return;
    const float x = pos[3*t+0], y = pos[3*t+1], z = pos[3*t+2];
    const float invx = (float)G / box[0];
    const float invy = (float)G / box[1];
    const float invz = (float)G / box[2];
    const int cx = min((int)(x * invx), G-1);
    const int cy = min((int)(y * invy), G-1);
    const int cz = min((int)(z * invz), G-1);
    const int cell = (cz*G + cy)*G + cx;
    const int slot = atomicAdd(&cnt[cell], 1);
    const float4 v = make_float4(x, y, z, __int_as_float(t));
    if (slot < BCAP) bucket[cell*BCAP + slot] = v;
    else {
        int o = atomicAdd(ovCnt, 1);
        if (o < OVCAP) ov[o] = v;   // oc>OVCAP detected query-side -> exact net
    }
}

// ---------- main: one wave/query.
// r18: staged loads + wrap-fold (one fadd/dim, bit-exact).
// r19 (this round):
//  - overflow entries 0..15 ride in round 6's dead lane-group (g==27), so the
//    common case is 7 rounds not 9; extra overflow rounds only when oc>16.
//  - path 3 (brute force) extracted to knn_exact cleanup kernel; failing waves
//    append to a fail list. Cuts VGPR pressure for all 8192 waves.
//  - rank-select epilogue reads 2 keys per ds_read (b128) with sentinel pad.

__global__ __launch_bounds__(256, 4) void knn_main(
    const float* __restrict__ pos, const float* __restrict__ box,
    const int* __restrict__ cnt, const int* __restrict__ ovCnt,
    const float4* __restrict__ ov, const float4* __restrict__ bucket,
    int* __restrict__ failCnt, int* __restrict__ failList,
    float* __restrict__ out, int N)
{
    const int lane = threadIdx.x & 63;
    const int wid  = threadIdx.x >> 6;
    const int i = blockIdx.x * 4 + wid;
    if (i >= N) return;

    __shared__ unsigned long long surv[4][CAP];   // 4 KB

    const float bx = box[0], by = box[1], bz = box[2];
    const float hx = 0.5f*bx, hy = 0.5f*by, hz = 0.5f*bz;
    const float invx = (float)G/bx, invy = (float)G/by, invz = (float)G/bz;
    const float cmin = fminf(bx, fminf(by, bz)) / (float)G;

    const float xi = pos[3*i+0], yi = pos[3*i+1], zi = pos[3*i+2];
    const int cx = min((int)(xi*invx), G-1);
    const int cy = min((int)(yi*invy), G-1);
    const int cz = min((int)(zi*invz), G-1);

    const long kN = (long)N * K;
    const int slot = lane & 15;       // bucket slot this lane reads
    const int gq   = lane >> 4;       // cell-subgroup 0..3

    int  M = 0;
    bool have = false;

    int  base = 0;
    bool bad  = false;

    // ballot/compact a candidate key into the wave's LDS survivor list
    auto flush = [&](unsigned long long key, unsigned long long tk) {
        const bool sv = (key <= tk);
        unsigned long long mk = __ballot(sv);
        int pc = __popcll(mk);
        if (base + pc <= CAP) {
            if (sv) {
                int below = __popcll(mk & ((1ULL << lane) - 1ULL));
                surv[wid][base + below] = key;
            }
        } else bad = true;
        base += pc;
    };

    // full min-image round (for overflow points of unknown origin cell)
    auto round_mi = [&](float4 pnt, bool valid, unsigned long long tk) {
        unsigned long long key = KEY_MAX;
        const int j = __float_as_int(pnt.w);
        if (valid && j != i) {
            float dx = __fsub_rn(xi, pnt.x);
            float dy = __fsub_rn(yi, pnt.y);
            float dz = __fsub_rn(zi, pnt.z);
            dx = dx > hx ? __fsub_rn(dx, bx) : (dx < -hx ? __fadd_rn(dx, bx) : dx);
            dy = dy > hy ? __fsub_rn(dy, by) : (dy < -hy ? __fadd_rn(dy, by) : dy);
            dz = dz > hz ? __fsub_rn(dz, bz) : (dz < -hz ? __fadd_rn(dz, bz) : dz);
            float cd = __fadd_rn(__fadd_rn(__fmul_rn(dx, dx), __fmul_rn(dy, dy)),
                                 __fmul_rn(dz, dz));
            key = ((unsigned long long)__float_as_uint(cd) << 13) | (unsigned)j;
        }
        flush(key, tk);
    };

    const int oc = ovCnt[0];

    // ================= PATH 1: staged loads, then ALU-only selection ==========
    {
        // ---- phase A: issue ALL loads back-to-back into registers, and
        //      precompute per-p wrap offsets from the cell coordinates.
        //      p==6, gq==3 (g==27 dummy) carries overflow entries 0..15.
        float4 pv[7]; int cv[7];
        float wox[6], woy[6], woz[6];
#pragma unroll
        for (int p = 0; p < 7; ++p) {
            const int g = 4*p + gq;            // 0..27
            const bool isOv = (p == 6) && (gq == 3);
            int cell = 0; float wx = 0.f, wy = 0.f, wz = 0.f;
            if (!isOv) {
                int ox = g % 3 - 1, oy = (g/3) % 3 - 1, oz = g/9 - 1;
                int ux = cx + ox;
                if (ux < 0)       { ux += G; wx =  bx; }
                else if (ux >= G) { ux -= G; wx = -bx; }
                int uy = cy + oy;
                if (uy < 0)       { uy += G; wy =  by; }
                else if (uy >= G) { uy -= G; wy = -by; }
                int uz = cz + oz;
                if (uz < 0)       { uz += G; wz =  bz; }
                else if (uz >= G) { uz -= G; wz = -bz; }
                cell = (uz*G + uy)*G + ux;
            }
            if (isOv) { cv[p] = oc; pv[p] = ov[slot]; }
            else      { cv[p] = cnt[cell]; pv[p] = bucket[cell*BCAP + slot]; }
            if (p < 6) { wox[p] = wx; woy[p] = wy; woz[p] = wz; }
        }

        // ---- phase B: straight-line ballot/compact from registers
        const float thr = cmin * cmin * 0.999f;
        const unsigned long long thrKey =
            ((unsigned long long)__float_as_uint(thr) << 13) | 0x1FFFULL;

        base = 0; bad = (oc > OVCAP);
#pragma unroll
        for (int p = 0; p < 6; ++p) {
            unsigned long long key = KEY_MAX;
            const float4 pnt = pv[p];
            const int j = __float_as_int(pnt.w);
            if ((slot < min(cv[p], BCAP)) && j != i) {
                // wrap folded into one fadd/dim (bit-exact, see r18 note)
                float dx = __fadd_rn(__fsub_rn(xi, pnt.x), wox[p]);
                float dy = __fadd_rn(__fsub_rn(yi, pnt.y), woy[p]);
                float dz = __fadd_rn(__fsub_rn(zi, pnt.z), woz[p]);
                float cd = __fadd_rn(__fadd_rn(__fmul_rn(dx, dx), __fmul_rn(dy, dy)),
                                     __fmul_rn(dz, dz));
                key = ((unsigned long long)__float_as_uint(cd) << 13) | (unsigned)j;
            }
            flush(key, thrKey);
        }
        // round 6: cells 24..26 (gq<3) + overflow[0..15] (gq==3) — full min-image
        // for all lanes (bit-identical to wrap-fold for the cell lanes).
        round_mi(pv[6], slot < min(cv[6], BCAP), thrKey);
        // rare overflow tail (oc>16)
        if (oc > 16) {
            round_mi(ov[min(16 + lane, OVCAP-1)], 16 + lane < oc, thrKey);
            if (oc > 80)
                round_mi(ov[min(80 + lane, OVCAP-1)], 80 + lane < oc, thrKey);
        }
        if (!bad && base >= K) { have = true; M = base; }
    }

    // ================= PATH 2: 125 cells at thr2 (rare ~10 queries) ==========
    if (!have && oc <= OVCAP) {
        const float thr2 = cmin * cmin * 1.9580f;   // (1.4*cmin)^2*0.999 < coverage 2*cmin
        const unsigned long long thrKey2 =
            ((unsigned long long)__float_as_uint(thr2) << 13) | 0x1FFFULL;

        base = 0; bad = false;
#pragma unroll 1
        for (int b = 0; b < 4; ++b) {
            // stage 8 rounds of loads back-to-back (one L2 latency per batch)
            float4 pv2[8]; int cv2[8]; bool gv2[8];
            float wx2[8], wy2[8], wz2[8];
#pragma unroll
            for (int q = 0; q < 8; ++q) {
                const int g = 4*(8*b + q) + gq;    // 0..127 (125.. dummy)
                gv2[q] = (g < 125);
                int cell = 0; float wx = 0.f, wy = 0.f, wz = 0.f;
                if (gv2[q]) {
                    int ox = g % 5 - 2, oy = (g/5) % 5 - 2, oz = g/25 - 2;
                    int ux = cx + ox;
                    if (ux < 0)       { ux += G; wx =  bx; }
                    else if (ux >= G) { ux -= G; wx = -bx; }
                    int uy = cy + oy;
                    if (uy < 0)       { uy += G; wy =  by; }
                    else if (uy >= G) { uy -= G; wy = -by; }
                    int uz = cz + oz;
                    if (uz < 0)       { uz += G; wz =  bz; }
                    else if (uz >= G) { uz -= G; wz = -bz; }
                    cell = (uz*G + uy)*G + ux;
                }
                cv2[q] = cnt[cell];
                pv2[q] = bucket[cell*BCAP + slot];
                wx2[q] = wx; wy2[q] = wy; wz2[q] = wz;
            }
#pragma unroll
            for (int q = 0; q < 8; ++q) {
                unsigned long long key = KEY_MAX;
                const float4 pnt = pv2[q];
                const int j = __float_as_int(pnt.w);
                if (gv2[q] && (slot < min(cv2[q], BCAP)) && j != i) {
                    float dx = __fadd_rn(__fsub_rn(xi, pnt.x), wx2[q]);
                    float dy = __fadd_rn(__fsub_rn(yi, pnt.y), wy2[q]);
                    float dz = __fadd_rn(__fsub_rn(zi, pnt.z), wz2[q]);
                    float cd = __fadd_rn(__fadd_rn(__fmul_rn(dx, dx), __fmul_rn(dy, dy)),
                                         __fmul_rn(dz, dz));
                    key = ((unsigned long long)__float_as_uint(cd) << 13) | (unsigned)j;
                }
                flush(key, thrKey2);
            }
        }
        if (!bad && oc > 0) {
            round_mi(ov[lane], lane < oc, thrKey2);
            if (oc > WAVE)
                round_mi(ov[WAVE + lane], WAVE + lane < oc, thrKey2);
        }
        if (!bad && base >= K) { have = true; M = base; }
    }

    // ================= shared epilogue: rank-select from LDS =================
    if (have) {
        if (lane == 0 && (M & 1)) surv[wid][M] = KEY_MAX;   // M odd => M<CAP, safe
        __asm__ __volatile__("s_waitcnt lgkmcnt(0)" ::: "memory");
        unsigned long long k0 = surv[wid][(lane < M) ? lane : 0];
        unsigned long long k1 = (lane + 64 < M) ? surv[wid][lane + 64] : KEY_MAX;
        int r0 = 0, r1 = 0;
        const int Me = (M + 1) & ~1;
#pragma unroll 2
        for (int m = 0; m < Me; m += 2) {
            const ulonglong2 s2 =
                *reinterpret_cast<const ulonglong2*>(&surv[wid][m]);
            r0 += (s2.x < k0) ? 1 : 0;
            r1 += (s2.x < k1) ? 1 : 0;
            r0 += (s2.y < k0) ? 1 : 0;
            r1 += (s2.y < k1) ? 1 : 0;
        }
        if (lane < K) out[(long)i*K + lane] = (float)i;
        if (lane < M && r0 < K) {
            out[kN + (long)i*K + r0]   = (float)(int)(k0 & 0x1FFFULL);
            out[2*kN + (long)i*K + r0] = __fsqrt_rn(__uint_as_float((unsigned)(k0 >> 13)));
        }
        if (lane + 64 < M && r1 < K) {
            out[kN + (long)i*K + r1]   = (float)(int)(k1 & 0x1FFFULL);
            out[2*kN + (long)i*K + r1] = __fsqrt_rn(__uint_as_float((unsigned)(k1 >> 13)));
        }
        return;
    }

    // ============ fail: append to cleanup list (brute force runs in knn_exact)
    if (lane == 0) {
        int f = atomicAdd(failCnt, 1);
        if (f < N) failList[f] = i;
    }
}

// ---------- cleanup: exactness net — brute force over pos for failed queries.
// Typically failCnt==0 and every wave exits immediately.

__global__ __launch_bounds__(256) void knn_exact(
    const float* __restrict__ pos, const float* __restrict__ box,
    const int* __restrict__ failCnt, const int* __restrict__ failList,
    float* __restrict__ out, int N)
{
    const int lane = threadIdx.x & 63;
    const int gw = (blockIdx.x * 256 + threadIdx.x) >> 6;   // global wave id
    const int nw = (gridDim.x * 256) >> 6;
    const int fc = min(failCnt[0], N);
    if (fc == 0) return;

    const float bx = box[0], by = box[1], bz = box[2];
    const float hx = 0.5f*bx, hy = 0.5f*by, hz = 0.5f*bz;
    const long kN = (long)N * K;

    for (int f = gw; f < fc; f += nw) {
        const int i = failList[f];
        const float xi = pos[3*i+0], yi = pos[3*i+1], zi = pos[3*i+2];

        float d[K]; int id[K];
#pragma unroll
        for (int m = 0; m < K; ++m) { d[m] = INFINITY; id[m] = 0x7fffffff; }

#pragma unroll 1
        for (int j0 = 0; j0 < N; j0 += WAVE) {
            const int j = j0 + lane;
            float cd = INFINITY; int ci = 0x7fffffff;
            if (j < N && j != i) {
                float dx = __fsub_rn(xi, pos[3*j+0]);
                float dy = __fsub_rn(yi, pos[3*j+1]);
                float dz = __fsub_rn(zi, pos[3*j+2]);
                dx = dx > hx ? __fsub_rn(dx, bx) : (dx < -hx ? __fadd_rn(dx, bx) : dx);
                dy = dy > hy ? __fsub_rn(dy, by) : (dy < -hy ? __fadd_rn(dy, by) : dy);
                dz = dz > hz ? __fsub_rn(dz, bz) : (dz < -hz ? __fadd_rn(dz, bz) : dz);
                cd = __fadd_rn(__fadd_rn(__fmul_rn(dx, dx), __fmul_rn(dy, dy)),
                               __fmul_rn(dz, dz));
                ci = j;
            }
            if (lex_less(cd, ci, d[K-1], id[K-1])) {
                bool lt[K];
#pragma unroll
                for (int m = 0; m < K; ++m) lt[m] = lex_less(cd, ci, d[m], id[m]);
#pragma unroll
                for (int m = K-1; m >= 1; --m) {
                    d[m]  = lt[m-1] ? d[m-1]  : (lt[m] ? cd : d[m]);
                    id[m] = lt[m-1] ? id[m-1] : (lt[m] ? ci : id[m]);
                }
                d[0]  = lt[0] ? cd : d[0];
                id[0] = lt[0] ? ci : id[0];
            }
        }

#pragma unroll 1
        for (int e = 0; e < K; ++e) {
            float bv = d[0]; int bi = id[0];
#pragma unroll
            for (int off = 32; off >= 1; off >>= 1) {
                float ov2 = __shfl_xor(bv, off, WAVE);
                int   oi = __shfl_xor(bi, off, WAVE);
                if (lex_less(ov2, oi, bv, bi)) { bv = ov2; bi = oi; }
            }
            if (d[0] == bv && id[0] == bi) {
#pragma unroll
                for (int m = 0; m < K-1; ++m) { d[m] = d[m+1]; id[m] = id[m+1]; }
                d[K-1] = INFINITY; id[K-1] = 0x7fffffff;
            }
            if (lane == e) {
                out[kN + (long)i*K + e]   = (float)bi;
                out[2*kN + (long)i*K + e] = __fsqrt_rn(bv);
            }
        }
        if (lane < K) out[(long)i*K + lane] = (float)i;
    }
}

extern "C" void kernel_launch(void* const* d_in, const int* in_sizes, int n_in,
                              void* d_out, int out_size, void* d_ws, size_t ws_size,
                              hipStream_t stream) {
    const float* pos = (const float*)d_in[0];
    const float* box = (const float*)d_in[1];
    const int N = in_sizes[0] / 3;

    unsigned char* ws = (unsigned char*)d_ws;
    int*    cnt      = (int*)ws;                    // CELLS ints @ 0        (4000 B)
    int*    ovCnt    = (int*)(ws + 4000);           // 1 int
    int*    failCnt  = (int*)(ws + 4004);           // 1 int
    float4* ov       = (float4*)(ws + 4096);        // OVCAP float4 (2 KB)
    float4* bucket   = (float4*)(ws + 8192);        // CELLS*BCAP float4 (256 KB)
    int*    failList = (int*)(ws + 270336);         // N ints

    hipMemsetAsync(cnt, 0, 4008, stream);           // cnt[1000] + ovCnt + failCnt
    prep_bucket<<<dim3((N + 255) / 256), dim3(256), 0, stream>>>(
        pos, box, cnt, ovCnt, ov, bucket, N);
    knn_main<<<dim3((N + 3) / 4), dim3(256), 0, stream>>>(
        pos, box, cnt, ovCnt, ov, bucket, failCnt, failList, (float*)d_out, N);
    knn_exact<<<dim3(64), dim3(256), 0, stream>>>(
        pos, box, failCnt, failList, (float*)d_out, N);
}

// Round 3
// 83.723 us; speedup vs baseline: 1.0244x; 1.0244x over previous
//
#include <hip/hip_runtime.h>
#include <math.h>

#define K 17
#define WAVE 64
#define G 10
#define CELLS (G*G*G)
#define BCAP 16       // bucket slots per cell
#define OVCAP 128     // global overflow list capacity (E[ov]~5)
#define CAP 128       // per-wave LDS survivor capacity
#define KEY_MAX 0xFFFFFFFFFFFFFFFFULL

__device__ __forceinline__ bool lex_less(float ad, int ai, float bd, int bi) {
    return (ad < bd) || (ad == bd && ai < bi);
}

// ---------- prep v3: scan-free padded buckets, fully parallel (r17-proven) ------

__global__ __launch_bounds__(256) void prep_bucket(
    const float* __restrict__ pos, const float* __restrict__ box,
    int* __restrict__ cnt, int* __restrict__ ovCnt,
    float4* __restrict__ ov, float4* __restrict__ bucket, int N)
{
    const int t = blockIdx.x * 256 + threadIdx.x;
    if (t >= N) return;
    const float x = pos[3*t+0], y = pos[3*t+1], z = pos[3*t+2];
    const float invx = (float)G / box[0];
    const float invy = (float)G / box[1];
    const float invz = (float)G / box[2];
    const int cx = min((int)(x * invx), G-1);
    const int cy = min((int)(y * invy), G-1);
    const int cz = min((int)(z * invz), G-1);
    const int cell = (cz*G + cy)*G + cx;
    const int slot = atomicAdd(&cnt[cell], 1);
    const float4 v = make_float4(x, y, z, __int_as_float(t));
    if (slot < BCAP) bucket[cell*BCAP + slot] = v;
    else {
        int o = atomicAdd(ovCnt, 1);
        if (o < OVCAP) ov[o] = v;   // oc>OVCAP detected query-side -> exact net
    }
}

// ---------- main: one wave/query.
// r18: staged loads + wrap-fold (one fadd/dim, bit-exact).
// r19: overflow folded into round 6's dead lane-group (7 rounds typical);
//      b128 rank-select epilogue.
// r20 (this round): union of r18+r19 WITHOUT the extra cleanup dispatch —
//      path 3 (brute force, ~0-10 queries) back inline; 3 dispatches total.
//      r2 showed the 4th launch ate the r19 trims; this keeps both.

__global__ __launch_bounds__(256, 4) void knn_main(
    const float* __restrict__ pos, const float* __restrict__ box,
    const int* __restrict__ cnt, const int* __restrict__ ovCnt,
    const float4* __restrict__ ov, const float4* __restrict__ bucket,
    float* __restrict__ out, int N)
{
    const int lane = threadIdx.x & 63;
    const int wid  = threadIdx.x >> 6;
    const int i = blockIdx.x * 4 + wid;
    if (i >= N) return;

    __shared__ unsigned long long surv[4][CAP];   // 4 KB

    const float bx = box[0], by = box[1], bz = box[2];
    const float hx = 0.5f*bx, hy = 0.5f*by, hz = 0.5f*bz;
    const float invx = (float)G/bx, invy = (float)G/by, invz = (float)G/bz;
    const float cmin = fminf(bx, fminf(by, bz)) / (float)G;

    const float xi = pos[3*i+0], yi = pos[3*i+1], zi = pos[3*i+2];
    const int cx = min((int)(xi*invx), G-1);
    const int cy = min((int)(yi*invy), G-1);
    const int cz = min((int)(zi*invz), G-1);

    const long kN = (long)N * K;
    const int slot = lane & 15;       // bucket slot this lane reads
    const int gq   = lane >> 4;       // cell-subgroup 0..3

    int  M = 0;
    bool have = false;

    int  base = 0;
    bool bad  = false;

    // ballot/compact a candidate key into the wave's LDS survivor list
    auto flush = [&](unsigned long long key, unsigned long long tk) {
        const bool sv = (key <= tk);
        unsigned long long mk = __ballot(sv);
        int pc = __popcll(mk);
        if (base + pc <= CAP) {
            if (sv) {
                int below = __popcll(mk & ((1ULL << lane) - 1ULL));
                surv[wid][base + below] = key;
            }
        } else bad = true;
        base += pc;
    };

    // full min-image round (for overflow points of unknown origin cell)
    auto round_mi = [&](float4 pnt, bool valid, unsigned long long tk) {
        unsigned long long key = KEY_MAX;
        const int j = __float_as_int(pnt.w);
        if (valid && j != i) {
            float dx = __fsub_rn(xi, pnt.x);
            float dy = __fsub_rn(yi, pnt.y);
            float dz = __fsub_rn(zi, pnt.z);
            dx = dx > hx ? __fsub_rn(dx, bx) : (dx < -hx ? __fadd_rn(dx, bx) : dx);
            dy = dy > hy ? __fsub_rn(dy, by) : (dy < -hy ? __fadd_rn(dy, by) : dy);
            dz = dz > hz ? __fsub_rn(dz, bz) : (dz < -hz ? __fadd_rn(dz, bz) : dz);
            float cd = __fadd_rn(__fadd_rn(__fmul_rn(dx, dx), __fmul_rn(dy, dy)),
                                 __fmul_rn(dz, dz));
            key = ((unsigned long long)__float_as_uint(cd) << 13) | (unsigned)j;
        }
        flush(key, tk);
    };

    const int oc = ovCnt[0];

    // ================= PATH 1: staged loads, then ALU-only selection ==========
    {
        // ---- phase A: issue ALL loads back-to-back into registers, and
        //      precompute per-p wrap offsets from the cell coordinates.
        //      p==6, gq==3 (g==27 dummy) carries overflow entries 0..15.
        float4 pv[7]; int cv[7];
        float wox[6], woy[6], woz[6];
#pragma unroll
        for (int p = 0; p < 7; ++p) {
            const int g = 4*p + gq;            // 0..27
            const bool isOv = (p == 6) && (gq == 3);
            int cell = 0; float wx = 0.f, wy = 0.f, wz = 0.f;
            if (!isOv) {
                int ox = g % 3 - 1, oy = (g/3) % 3 - 1, oz = g/9 - 1;
                int ux = cx + ox;
                if (ux < 0)       { ux += G; wx =  bx; }
                else if (ux >= G) { ux -= G; wx = -bx; }
                int uy = cy + oy;
                if (uy < 0)       { uy += G; wy =  by; }
                else if (uy >= G) { uy -= G; wy = -by; }
                int uz = cz + oz;
                if (uz < 0)       { uz += G; wz =  bz; }
                else if (uz >= G) { uz -= G; wz = -bz; }
                cell = (uz*G + uy)*G + ux;
            }
            if (isOv) { cv[p] = oc; pv[p] = ov[slot]; }
            else      { cv[p] = cnt[cell]; pv[p] = bucket[cell*BCAP + slot]; }
            if (p < 6) { wox[p] = wx; woy[p] = wy; woz[p] = wz; }
        }

        // ---- phase B: straight-line ballot/compact from registers
        const float thr = cmin * cmin * 0.999f;
        const unsigned long long thrKey =
            ((unsigned long long)__float_as_uint(thr) << 13) | 0x1FFFULL;

        base = 0; bad = (oc > OVCAP);
#pragma unroll
        for (int p = 0; p < 6; ++p) {
            unsigned long long key = KEY_MAX;
            const float4 pnt = pv[p];
            const int j = __float_as_int(pnt.w);
            if ((slot < min(cv[p], BCAP)) && j != i) {
                // wrap folded into one fadd/dim (bit-exact, see r18 note)
                float dx = __fadd_rn(__fsub_rn(xi, pnt.x), wox[p]);
                float dy = __fadd_rn(__fsub_rn(yi, pnt.y), woy[p]);
                float dz = __fadd_rn(__fsub_rn(zi, pnt.z), woz[p]);
                float cd = __fadd_rn(__fadd_rn(__fmul_rn(dx, dx), __fmul_rn(dy, dy)),
                                     __fmul_rn(dz, dz));
                key = ((unsigned long long)__float_as_uint(cd) << 13) | (unsigned)j;
            }
            flush(key, thrKey);
        }
        // round 6: cells 24..26 (gq<3) + overflow[0..15] (gq==3) — full min-image
        // for all lanes (bit-identical to wrap-fold for the cell lanes).
        round_mi(pv[6], slot < min(cv[6], BCAP), thrKey);
        // rare overflow tail (oc>16)
        if (oc > 16) {
            round_mi(ov[min(16 + lane, OVCAP-1)], 16 + lane < oc, thrKey);
            if (oc > 80)
                round_mi(ov[min(80 + lane, OVCAP-1)], 80 + lane < oc, thrKey);
        }
        if (!bad && base >= K) { have = true; M = base; }
    }

    // ================= PATH 2: 125 cells at thr2 (rare ~10 queries) ==========
    if (!have && oc <= OVCAP) {
        const float thr2 = cmin * cmin * 1.9580f;   // (1.4*cmin)^2*0.999 < coverage 2*cmin
        const unsigned long long thrKey2 =
            ((unsigned long long)__float_as_uint(thr2) << 13) | 0x1FFFULL;

        base = 0; bad = false;
#pragma unroll 1
        for (int b = 0; b < 4; ++b) {
            // stage 8 rounds of loads back-to-back (one L2 latency per batch)
            float4 pv2[8]; int cv2[8]; bool gv2[8];
            float wx2[8], wy2[8], wz2[8];
#pragma unroll
            for (int q = 0; q < 8; ++q) {
                const int g = 4*(8*b + q) + gq;    // 0..127 (125.. dummy)
                gv2[q] = (g < 125);
                int cell = 0; float wx = 0.f, wy = 0.f, wz = 0.f;
                if (gv2[q]) {
                    int ox = g % 5 - 2, oy = (g/5) % 5 - 2, oz = g/25 - 2;
                    int ux = cx + ox;
                    if (ux < 0)       { ux += G; wx =  bx; }
                    else if (ux >= G) { ux -= G; wx = -bx; }
                    int uy = cy + oy;
                    if (uy < 0)       { uy += G; wy =  by; }
                    else if (uy >= G) { uy -= G; wy = -by; }
                    int uz = cz + oz;
                    if (uz < 0)       { uz += G; wz =  bz; }
                    else if (uz >= G) { uz -= G; wz = -bz; }
                    cell = (uz*G + uy)*G + ux;
                }
                cv2[q] = cnt[cell];
                pv2[q] = bucket[cell*BCAP + slot];
                wx2[q] = wx; wy2[q] = wy; wz2[q] = wz;
            }
#pragma unroll
            for (int q = 0; q < 8; ++q) {
                unsigned long long key = KEY_MAX;
                const float4 pnt = pv2[q];
                const int j = __float_as_int(pnt.w);
                if (gv2[q] && (slot < min(cv2[q], BCAP)) && j != i) {
                    float dx = __fadd_rn(__fsub_rn(xi, pnt.x), wx2[q]);
                    float dy = __fadd_rn(__fsub_rn(yi, pnt.y), wy2[q]);
                    float dz = __fadd_rn(__fsub_rn(zi, pnt.z), wz2[q]);
                    float cd = __fadd_rn(__fadd_rn(__fmul_rn(dx, dx), __fmul_rn(dy, dy)),
                                         __fmul_rn(dz, dz));
                    key = ((unsigned long long)__float_as_uint(cd) << 13) | (unsigned)j;
                }
                flush(key, thrKey2);
            }
        }
        if (!bad && oc > 0) {
            round_mi(ov[lane], lane < oc, thrKey2);
            if (oc > WAVE)
                round_mi(ov[WAVE + lane], WAVE + lane < oc, thrKey2);
        }
        if (!bad && base >= K) { have = true; M = base; }
    }

    // ================= shared epilogue: rank-select from LDS =================
    if (have) {
        if (lane == 0 && (M & 1)) surv[wid][M] = KEY_MAX;   // M odd => M<CAP, safe
        __asm__ __volatile__("s_waitcnt lgkmcnt(0)" ::: "memory");
        unsigned long long k0 = surv[wid][(lane < M) ? lane : 0];
        unsigned long long k1 = (lane + 64 < M) ? surv[wid][lane + 64] : KEY_MAX;
        int r0 = 0, r1 = 0;
        const int Me = (M + 1) & ~1;
#pragma unroll 2
        for (int m = 0; m < Me; m += 2) {
            const ulonglong2 s2 =
                *reinterpret_cast<const ulonglong2*>(&surv[wid][m]);
            r0 += (s2.x < k0) ? 1 : 0;
            r1 += (s2.x < k1) ? 1 : 0;
            r0 += (s2.y < k0) ? 1 : 0;
            r1 += (s2.y < k1) ? 1 : 0;
        }
        if (lane < K) out[(long)i*K + lane] = (float)i;
        if (lane < M && r0 < K) {
            out[kN + (long)i*K + r0]   = (float)(int)(k0 & 0x1FFFULL);
            out[2*kN + (long)i*K + r0] = __fsqrt_rn(__uint_as_float((unsigned)(k0 >> 13)));
        }
        if (lane + 64 < M && r1 < K) {
            out[kN + (long)i*K + r1]   = (float)(int)(k1 & 0x1FFFULL);
            out[2*kN + (long)i*K + r1] = __fsqrt_rn(__uint_as_float((unsigned)(k1 >> 13)));
        }
        return;
    }

    // ============ PATH 3: exactness net — brute force over pos (r1-proven) ======
    {
        float d[K]; int id[K];
#pragma unroll
        for (int m = 0; m < K; ++m) { d[m] = INFINITY; id[m] = 0x7fffffff; }

#pragma unroll 1
        for (int j0 = 0; j0 < N; j0 += WAVE) {
            const int j = j0 + lane;
            float cd = INFINITY; int ci = 0x7fffffff;
            if (j < N && j != i) {
                float dx = __fsub_rn(xi, pos[3*j+0]);
                float dy = __fsub_rn(yi, pos[3*j+1]);
                float dz = __fsub_rn(zi, pos[3*j+2]);
                dx = dx > hx ? __fsub_rn(dx, bx) : (dx < -hx ? __fadd_rn(dx, bx) : dx);
                dy = dy > hy ? __fsub_rn(dy, by) : (dy < -hy ? __fadd_rn(dy, by) : dy);
                dz = dz > hz ? __fsub_rn(dz, bz) : (dz < -hz ? __fadd_rn(dz, bz) : dz);
                cd = __fadd_rn(__fadd_rn(__fmul_rn(dx, dx), __fmul_rn(dy, dy)),
                               __fmul_rn(dz, dz));
                ci = j;
            }
            if (lex_less(cd, ci, d[K-1], id[K-1])) {
                bool lt[K];
#pragma unroll
                for (int m = 0; m < K; ++m) lt[m] = lex_less(cd, ci, d[m], id[m]);
#pragma unroll
                for (int m = K-1; m >= 1; --m) {
                    d[m]  = lt[m-1] ? d[m-1]  : (lt[m] ? cd : d[m]);
                    id[m] = lt[m-1] ? id[m-1] : (lt[m] ? ci : id[m]);
                }
                d[0]  = lt[0] ? cd : d[0];
                id[0] = lt[0] ? ci : id[0];
            }
        }

#pragma unroll 1
        for (int e = 0; e < K; ++e) {
            float bv = d[0]; int bi = id[0];
#pragma unroll
            for (int off = 32; off >= 1; off >>= 1) {
                float ov2 = __shfl_xor(bv, off, WAVE);
                int   oi = __shfl_xor(bi, off, WAVE);
                if (lex_less(ov2, oi, bv, bi)) { bv = ov2; bi = oi; }
            }
            if (d[0] == bv && id[0] == bi) {
#pragma unroll
                for (int m = 0; m < K-1; ++m) { d[m] = d[m+1]; id[m] = id[m+1]; }
                d[K-1] = INFINITY; id[K-1] = 0x7fffffff;
            }
            if (lane == e) {
                out[kN + (long)i*K + e]   = (float)bi;
                out[2*kN + (long)i*K + e] = __fsqrt_rn(bv);
            }
        }
        if (lane < K) out[(long)i*K + lane] = (float)i;
    }
}

extern "C" void kernel_launch(void* const* d_in, const int* in_sizes, int n_in,
                              void* d_out, int out_size, void* d_ws, size_t ws_size,
                              hipStream_t stream) {
    const float* pos = (const float*)d_in[0];
    const float* box = (const float*)d_in[1];
    const int N = in_sizes[0] / 3;

    unsigned char* ws = (unsigned char*)d_ws;
    int*    cnt    = (int*)ws;                    // CELLS ints @ 0
    int*    ovCnt  = (int*)(ws + 4000);           // 1 int
    float4* ov     = (float4*)(ws + 4096);        // OVCAP float4 (2 KB)
    float4* bucket = (float4*)(ws + 8192);        // CELLS*BCAP float4 (256 KB)

    hipMemsetAsync(cnt, 0, 4004, stream);         // cnt[1000] + ovCnt
    prep_bucket<<<dim3((N + 255) / 256), dim3(256), 0, stream>>>(
        pos, box, cnt, ovCnt, ov, bucket, N);
    knn_main<<<dim3((N + 3) / 4), dim3(256), 0, stream>>>(
        pos, box, cnt, ovCnt, ov, bucket, (float*)d_out, N);
}